// Round 1
// baseline (3484.298 us; speedup 1.0000x reference)
//
#include <hip/hip_runtime.h>
#include <math.h>

#define LOG2E 1.4426950408889634f

__device__ __forceinline__ float rcp_f(float x){ return __builtin_amdgcn_rcpf(x); }
__device__ __forceinline__ float exp2_f(float x){ return __builtin_amdgcn_exp2f(x); }
__device__ __forceinline__ float sigmoid_f(float x){ return rcp_f(1.0f + exp2_f(-x*LOG2E)); }
__device__ __forceinline__ float tanh_f(float x){
  x = fminf(fmaxf(x, -20.0f), 20.0f);
  float u = exp2_f(x * (2.0f*LOG2E));        // e^{2x}
  return (u - 1.0f) * rcp_f(u + 1.0f);
}

// ---------------- K0: pack nonlinearity tables ----------------
// rec_tab layout: [k][tid] float4 {sig_l2, musig_l2, w, w*erev}; tid: s=tid>>3, j=(tid&7)*16+k
// sens_tab layout: [half][k][tid] float4; tid: s=half*64+(tid>>4), i=(tid&15)*16+k
__global__ __launch_bounds__(256) void k0_prep(
    const float* __restrict__ w, const float* __restrict__ sigma, const float* __restrict__ mu,
    const float* __restrict__ erev, const float* __restrict__ smask_r,
    const float* __restrict__ sw, const float* __restrict__ ssigma, const float* __restrict__ smu,
    const float* __restrict__ serev, const float* __restrict__ smask_s,
    float* __restrict__ rec_tab, float* __restrict__ sens_tab){
  int p = blockIdx.x*256 + threadIdx.x;     // 49152 total
  if(p < 16384){
    int k = p >> 10, t5 = p & 1023;
    int s = t5 >> 3, j = (t5 & 7)*16 + k;
    int idx = j*128 + s;
    float sg = sigma[idx], m = mu[idx], wv = w[idx]*smask_r[idx], er = erev[idx];
    float4 o; o.x = sg*LOG2E; o.y = m*sg*LOG2E; o.z = wv; o.w = wv*er;
    *(float4*)(rec_tab + (size_t)p*4) = o;
  } else {
    int q = p - 16384;
    int half = q >> 14, r = q & 16383, k = r >> 10, t5 = r & 1023;
    int s = half*64 + (t5 >> 4), i = (t5 & 15)*16 + k;
    int idx = i*128 + s;
    float sg = ssigma[idx], m = smu[idx], wv = sw[idx]*smask_s[idx], er = serev[idx];
    float4 o; o.x = sg*LOG2E; o.y = m*sg*LOG2E; o.z = wv; o.w = wv*er;
    *(float4*)(sens_tab + (size_t)q*4) = o;
  }
}

// ---------------- K1: proj = tanh(X@W_in + b_in); split hidden / transposed gate ----------------
__global__ __launch_bounds__(256) void k1_gemm_tanh(
    const float* __restrict__ A, const float* __restrict__ Wb, const float* __restrict__ bias,
    float* __restrict__ hidden, float* __restrict__ gatet){
  __shared__ float As[64][36];
  __shared__ float Bs[32][64];
  __shared__ float trans[64][68];
  int wg = blockIdx.x;                    // 1024*6
  int ntile = wg % 6, mtile = wg / 6;
  int row0 = mtile*64, col0 = ntile*64;
  int tid = threadIdx.x, tr = tid>>4, tc = tid&15;
  float acc[4][4] = {};
  for(int k0=0;k0<512;k0+=32){
    __syncthreads();
    #pragma unroll
    for(int l=0;l<2;l++){
      int idx = tid + l*256; int r = idx>>3, c4 = idx&7;
      *(float4*)&As[r][c4*4] = *(const float4*)(A + (size_t)(row0+r)*512 + k0 + c4*4);
    }
    #pragma unroll
    for(int l=0;l<2;l++){
      int idx = tid + l*256; int r = idx>>4, c4 = idx&15;
      *(float4*)&Bs[r][c4*4] = *(const float4*)(Wb + (size_t)(k0+r)*384 + col0 + c4*4);
    }
    __syncthreads();
    #pragma unroll
    for(int k=0;k<32;k++){
      float a0=As[tr*4+0][k],a1=As[tr*4+1][k],a2=As[tr*4+2][k],a3=As[tr*4+3][k];
      float4 b4 = *(float4*)&Bs[k][tc*4];
      acc[0][0]=fmaf(a0,b4.x,acc[0][0]); acc[0][1]=fmaf(a0,b4.y,acc[0][1]); acc[0][2]=fmaf(a0,b4.z,acc[0][2]); acc[0][3]=fmaf(a0,b4.w,acc[0][3]);
      acc[1][0]=fmaf(a1,b4.x,acc[1][0]); acc[1][1]=fmaf(a1,b4.y,acc[1][1]); acc[1][2]=fmaf(a1,b4.z,acc[1][2]); acc[1][3]=fmaf(a1,b4.w,acc[1][3]);
      acc[2][0]=fmaf(a2,b4.x,acc[2][0]); acc[2][1]=fmaf(a2,b4.y,acc[2][1]); acc[2][2]=fmaf(a2,b4.z,acc[2][2]); acc[2][3]=fmaf(a2,b4.w,acc[2][3]);
      acc[3][0]=fmaf(a3,b4.x,acc[3][0]); acc[3][1]=fmaf(a3,b4.y,acc[3][1]); acc[3][2]=fmaf(a3,b4.z,acc[3][2]); acc[3][3]=fmaf(a3,b4.w,acc[3][3]);
    }
  }
  float bv[4];
  #pragma unroll
  for(int j=0;j<4;j++) bv[j] = bias[col0 + tc*4 + j];
  if(col0 < 256){
    #pragma unroll
    for(int i=0;i<4;i++){
      float4 o;
      o.x = tanh_f(acc[i][0]+bv[0]); o.y = tanh_f(acc[i][1]+bv[1]);
      o.z = tanh_f(acc[i][2]+bv[2]); o.w = tanh_f(acc[i][3]+bv[3]);
      *(float4*)(hidden + (size_t)(row0+tr*4+i)*256 + col0 + tc*4) = o;
    }
  } else {
    #pragma unroll
    for(int i=0;i<4;i++)
      #pragma unroll
      for(int j=0;j<4;j++)
        trans[tc*4+j][tr*4+i] = tanh_f(acc[i][j]+bv[j]);
    __syncthreads();
    int b = row0 >> 10, t0 = row0 & 1023;
    int sl = tid >> 2, q = tid & 3;
    size_t base = ((size_t)b*128 + (col0-256) + sl)*1024 + t0 + q*16;
    const float* src = &trans[sl][q*16];
    #pragma unroll
    for(int l=0;l<4;l++)
      *(float4*)(gatet + base + l*4) = *(const float4*)(src + l*4);
  }
}

// ---------------- K2: softmax over T per (b,s) row, then sigmoid; in-place on gatet ----------------
__global__ __launch_bounds__(256) void k2_softmax_sig(float* __restrict__ gatet){
  __shared__ float red[8];
  size_t row = blockIdx.x;                 // 8192
  float* p = gatet + row*1024;
  int tid = threadIdx.x;
  float4 x = *(const float4*)(p + tid*4);
  float mx = fmaxf(fmaxf(x.x,x.y), fmaxf(x.z,x.w));
  #pragma unroll
  for(int d=1; d<64; d<<=1) mx = fmaxf(mx, __shfl_xor(mx, d));
  if((tid&63)==0) red[tid>>6] = mx;
  __syncthreads();
  mx = fmaxf(fmaxf(red[0],red[1]), fmaxf(red[2],red[3]));
  float4 e;
  e.x = exp2_f((x.x-mx)*LOG2E); e.y = exp2_f((x.y-mx)*LOG2E);
  e.z = exp2_f((x.z-mx)*LOG2E); e.w = exp2_f((x.w-mx)*LOG2E);
  float sm = e.x+e.y+e.z+e.w;
  #pragma unroll
  for(int d=1; d<64; d<<=1) sm += __shfl_xor(sm, d);
  if((tid&63)==0) red[4+(tid>>6)] = sm;
  __syncthreads();
  sm = red[4]+red[5]+red[6]+red[7];
  float r = rcp_f(sm);
  float4 o;
  o.x = sigmoid_f(e.x*r); o.y = sigmoid_f(e.y*r);
  o.z = sigmoid_f(e.z*r); o.w = sigmoid_f(e.w*r);
  *(float4*)(p + tid*4) = o;
}

// ---------------- K3: CG = (hidden@W_c + b_c) * gsig ----------------
__global__ __launch_bounds__(256) void k3_cgemm(
    const float* __restrict__ A, const float* __restrict__ Wb, const float* __restrict__ bias,
    const float* __restrict__ gsigt, float* __restrict__ CG){
  __shared__ float As[64][36];
  __shared__ float Bs[32][64];
  int wg = blockIdx.x;                     // 1024*2
  int ntile = wg & 1, mtile = wg >> 1;
  int row0 = mtile*64, col0 = ntile*64;
  int tid = threadIdx.x, tr = tid>>4, tc = tid&15;
  float acc[4][4] = {};
  for(int k0=0;k0<256;k0+=32){
    __syncthreads();
    #pragma unroll
    for(int l=0;l<2;l++){
      int idx = tid + l*256; int r = idx>>3, c4 = idx&7;
      *(float4*)&As[r][c4*4] = *(const float4*)(A + (size_t)(row0+r)*256 + k0 + c4*4);
    }
    #pragma unroll
    for(int l=0;l<2;l++){
      int idx = tid + l*256; int r = idx>>4, c4 = idx&15;
      *(float4*)&Bs[r][c4*4] = *(const float4*)(Wb + (size_t)(k0+r)*128 + col0 + c4*4);
    }
    __syncthreads();
    #pragma unroll
    for(int k=0;k<32;k++){
      float a0=As[tr*4+0][k],a1=As[tr*4+1][k],a2=As[tr*4+2][k],a3=As[tr*4+3][k];
      float4 b4 = *(float4*)&Bs[k][tc*4];
      acc[0][0]=fmaf(a0,b4.x,acc[0][0]); acc[0][1]=fmaf(a0,b4.y,acc[0][1]); acc[0][2]=fmaf(a0,b4.z,acc[0][2]); acc[0][3]=fmaf(a0,b4.w,acc[0][3]);
      acc[1][0]=fmaf(a1,b4.x,acc[1][0]); acc[1][1]=fmaf(a1,b4.y,acc[1][1]); acc[1][2]=fmaf(a1,b4.z,acc[1][2]); acc[1][3]=fmaf(a1,b4.w,acc[1][3]);
      acc[2][0]=fmaf(a2,b4.x,acc[2][0]); acc[2][1]=fmaf(a2,b4.y,acc[2][1]); acc[2][2]=fmaf(a2,b4.z,acc[2][2]); acc[2][3]=fmaf(a2,b4.w,acc[2][3]);
      acc[3][0]=fmaf(a3,b4.x,acc[3][0]); acc[3][1]=fmaf(a3,b4.y,acc[3][1]); acc[3][2]=fmaf(a3,b4.z,acc[3][2]); acc[3][3]=fmaf(a3,b4.w,acc[3][3]);
    }
  }
  int b = row0 >> 10, t0 = row0 & 1023;
  float bv[4];
  #pragma unroll
  for(int j=0;j<4;j++) bv[j] = bias[col0 + tc*4 + j];
  #pragma unroll
  for(int i=0;i<4;i++){
    int t = t0 + tr*4 + i;
    float4 o;
    o.x = (acc[i][0]+bv[0]) * gsigt[((size_t)b*128 + col0+tc*4+0)*1024 + t];
    o.y = (acc[i][1]+bv[1]) * gsigt[((size_t)b*128 + col0+tc*4+1)*1024 + t];
    o.z = (acc[i][2]+bv[2]) * gsigt[((size_t)b*128 + col0+tc*4+2)*1024 + t];
    o.w = (acc[i][3]+bv[3]) * gsigt[((size_t)b*128 + col0+tc*4+3)*1024 + t];
    *(float4*)(CG + (size_t)(row0+tr*4+i)*128 + col0 + tc*4) = o;
  }
}

#define SIGACC(TT, VV) { float x_ = (TT).y - (VV)*(TT).x; float sg_ = rcp_f(1.0f + exp2_f(x_)); \
                         num = fmaf((TT).w, sg_, num); den = fmaf((TT).z, sg_, den); }

// ---------------- K4: sensory w_num_s / w_den_s for all (b,t,s) ----------------
__global__ __launch_bounds__(1024) void k4_sensory(
    const float* __restrict__ sens_tab, const float* __restrict__ hidden,
    float* __restrict__ wns, float* __restrict__ wds){
  int wg = blockIdx.x;                     // 256
  int half = wg & 1;
  int btbase = wg >> 1;                    // 0..127
  int tid = threadIdx.x;
  float4 tab[16];
  #pragma unroll
  for(int k=0;k<16;k++) tab[k] = *(const float4*)(sens_tab + ((size_t)half*16384 + k*1024 + tid)*4);
  __shared__ float h_lds[320];
  __shared__ float res[128];
  int sloc = tid >> 4, ig = tid & 15;
  for(int bt = btbase; bt < 65536; bt += 128){
    __syncthreads();
    if(tid < 64){
      float4 hv = *(const float4*)(hidden + (size_t)bt*256 + tid*4);
      *(float4*)&h_lds[tid*4 + (tid>>2)*4] = hv;
    }
    __syncthreads();
    float num = 0.f, den = 0.f;
    #pragma unroll
    for(int k4=0;k4<4;k4++){
      float4 h4 = *(const float4*)&h_lds[ig*20 + k4*4];
      SIGACC(tab[k4*4+0], h4.x); SIGACC(tab[k4*4+1], h4.y);
      SIGACC(tab[k4*4+2], h4.z); SIGACC(tab[k4*4+3], h4.w);
    }
    num += __shfl_xor(num,1); den += __shfl_xor(den,1);
    num += __shfl_xor(num,2); den += __shfl_xor(den,2);
    num += __shfl_xor(num,4); den += __shfl_xor(den,4);
    num += __shfl_xor(num,8); den += __shfl_xor(den,8);
    if(ig==0){ res[sloc] = num; res[64+sloc] = den; }
    __syncthreads();
    if(tid < 64)       wns[(size_t)bt*128 + half*64 + tid] = res[tid];
    else if(tid < 128) wds[(size_t)bt*128 + half*64 + (tid-64)] = res[tid];
  }
}

// ---------------- K5: chunked-parallel recurrence ----------------
// 4 chunks x 64 batches = 256 WGs; chunk len 256, warmup 16 steps (contraction ~0.1/step)
__global__ __launch_bounds__(1024) void k5_recur(
    const float* __restrict__ rec_tab, const float* __restrict__ wns, const float* __restrict__ wds,
    const float* __restrict__ CG, const float* __restrict__ cm, const float* __restrict__ gleak,
    const float* __restrict__ vleak, const float* __restrict__ ode0,
    float* __restrict__ out_fused, float* __restrict__ out_state){
  int wg = blockIdx.x;                     // 256
  int g = wg >> 6;                         // chunk 0..3
  int b = wg & 63;
  int tid = threadIdx.x;
  int s = tid >> 3, jg = tid & 7;
  float4 tab[16];
  #pragma unroll
  for(int k=0;k<16;k++) tab[k] = *(const float4*)(rec_tab + ((size_t)k*1024 + tid)*4);
  float cmt = cm[s]*6.0f;
  float gl  = gleak[s];
  float glv = gl*vleak[s];
  __shared__ float vbuf[2][160];
  __shared__ float wns_s[128];
  __shared__ float wds_s[128];
  if(tid < 128){
    float v0 = (g==0) ? ode0[b*128 + tid] : 0.0f;
    vbuf[0][tid + (tid>>4)*4] = v0;
  }
  int tstart = (g==0) ? 0 : g*256 - 16;
  int tend   = (g+1)*256;
  int tout   = g*256;
  int cur = 0;
  __syncthreads();
  for(int t=tstart; t<tend; t++){
    if(tid < 128)      wns_s[tid]     = wns[((size_t)b*1024 + t)*128 + tid];
    else if(tid < 256) wds_s[tid-128] = wds[((size_t)b*1024 + t)*128 + (tid-128)];
    __syncthreads();
    #pragma unroll
    for(int u=0; u<6; u++){
      float num = 0.f, den = 0.f;
      const float* vb = vbuf[cur];
      #pragma unroll
      for(int k4=0;k4<4;k4++){
        float4 v4 = *(const float4*)(vb + jg*20 + k4*4);
        SIGACC(tab[k4*4+0], v4.x); SIGACC(tab[k4*4+1], v4.y);
        SIGACC(tab[k4*4+2], v4.z); SIGACC(tab[k4*4+3], v4.w);
      }
      num += __shfl_xor(num,1); den += __shfl_xor(den,1);
      num += __shfl_xor(num,2); den += __shfl_xor(den,2);
      num += __shfl_xor(num,4); den += __shfl_xor(den,4);
      if(jg==0){
        float vold = vb[s + (s>>4)*4];
        float nn = fmaf(cmt, vold, glv) + num + wns_s[s];
        float dd = cmt + gl + den + wds_s[s] + 1e-8f;
        vbuf[cur^1][s + (s>>4)*4] = nn * rcp_f(dd);
      }
      cur ^= 1;
      __syncthreads();
    }
    if(t >= tout && tid < 128){
      float vv  = vbuf[cur][tid + (tid>>4)*4];
      float cgv = CG[((size_t)b*1024 + t)*128 + tid];
      out_fused[((size_t)b*1024 + t)*128 + tid] = vv * cgv;
    }
  }
  if(g==3 && tid<128) out_state[b*128 + tid] = vbuf[cur][tid + (tid>>4)*4];
}

// ---------------- K6: outputs = fused @ W_out + b_out ----------------
__global__ __launch_bounds__(256) void k6_ogemm(
    const float* __restrict__ A, const float* __restrict__ Wb, const float* __restrict__ bias,
    float* __restrict__ out0){
  __shared__ float As[64][36];
  __shared__ float Bs[32][64];
  int mtile = blockIdx.x;                  // 1024
  int row0 = mtile*64;
  int tid = threadIdx.x, tr = tid>>4, tc = tid&15;
  float acc[4][4] = {};
  for(int k0=0;k0<128;k0+=32){
    __syncthreads();
    #pragma unroll
    for(int l=0;l<2;l++){
      int idx = tid + l*256; int r = idx>>3, c4 = idx&7;
      *(float4*)&As[r][c4*4] = *(const float4*)(A + (size_t)(row0+r)*128 + k0 + c4*4);
    }
    #pragma unroll
    for(int l=0;l<2;l++){
      int idx = tid + l*256; int r = idx>>4, c4 = idx&15;
      *(float4*)&Bs[r][c4*4] = *(const float4*)(Wb + (size_t)(k0+r)*64 + c4*4);
    }
    __syncthreads();
    #pragma unroll
    for(int k=0;k<32;k++){
      float a0=As[tr*4+0][k],a1=As[tr*4+1][k],a2=As[tr*4+2][k],a3=As[tr*4+3][k];
      float4 b4 = *(float4*)&Bs[k][tc*4];
      acc[0][0]=fmaf(a0,b4.x,acc[0][0]); acc[0][1]=fmaf(a0,b4.y,acc[0][1]); acc[0][2]=fmaf(a0,b4.z,acc[0][2]); acc[0][3]=fmaf(a0,b4.w,acc[0][3]);
      acc[1][0]=fmaf(a1,b4.x,acc[1][0]); acc[1][1]=fmaf(a1,b4.y,acc[1][1]); acc[1][2]=fmaf(a1,b4.z,acc[1][2]); acc[1][3]=fmaf(a1,b4.w,acc[1][3]);
      acc[2][0]=fmaf(a2,b4.x,acc[2][0]); acc[2][1]=fmaf(a2,b4.y,acc[2][1]); acc[2][2]=fmaf(a2,b4.z,acc[2][2]); acc[2][3]=fmaf(a2,b4.w,acc[2][3]);
      acc[3][0]=fmaf(a3,b4.x,acc[3][0]); acc[3][1]=fmaf(a3,b4.y,acc[3][1]); acc[3][2]=fmaf(a3,b4.z,acc[3][2]); acc[3][3]=fmaf(a3,b4.w,acc[3][3]);
    }
  }
  float bv[4];
  #pragma unroll
  for(int j=0;j<4;j++) bv[j] = bias[tc*4 + j];
  #pragma unroll
  for(int i=0;i<4;i++){
    float4 o;
    o.x = acc[i][0]+bv[0]; o.y = acc[i][1]+bv[1];
    o.z = acc[i][2]+bv[2]; o.w = acc[i][3]+bv[3];
    *(float4*)(out0 + (size_t)(row0+tr*4+i)*64 + tc*4) = o;
  }
}

extern "C" void kernel_launch(void* const* d_in, const int* in_sizes, int n_in,
                              void* d_out, int out_size, void* d_ws, size_t ws_size,
                              hipStream_t stream) {
  const float* inputs = (const float*)d_in[0];
  const float* ode0   = (const float*)d_in[1];
  const float* W_in   = (const float*)d_in[2];
  const float* b_in   = (const float*)d_in[3];
  const float* W_c    = (const float*)d_in[4];
  const float* b_c    = (const float*)d_in[5];
  const float* W_out  = (const float*)d_in[6];
  const float* b_out  = (const float*)d_in[7];
  const float* gleak  = (const float*)d_in[8];
  const float* vleak  = (const float*)d_in[9];
  const float* cm     = (const float*)d_in[10];
  const float* w      = (const float*)d_in[11];
  const float* sigma  = (const float*)d_in[12];
  const float* mu     = (const float*)d_in[13];
  const float* sw     = (const float*)d_in[14];
  const float* ssig   = (const float*)d_in[15];
  const float* smu    = (const float*)d_in[16];
  const float* erev   = (const float*)d_in[17];
  const float* serev  = (const float*)d_in[18];
  const float* mask   = (const float*)d_in[19];
  const float* smask  = (const float*)d_in[20];

  float* out0 = (float*)d_out;                         // (B,T,M) = 64*1024*64
  float* out1 = out0 + (size_t)64*1024*64;             // (B,S)
  float* out2 = out1 + (size_t)64*128;                 // (B,T,S)

  float* ws       = (float*)d_ws;
  float* hidden   = ws;                       // 16,777,216 f
  float* gatet    = hidden   + 16777216;      //  8,388,608 f  (b,s,t) -> becomes gsig in-place
  float* CG       = gatet    + 8388608;       //  8,388,608 f  (b,t,s)
  float* wnsA     = CG       + 8388608;       //  8,388,608 f
  float* wdsA     = wnsA     + 8388608;       //  8,388,608 f
  float* rec_tab  = wdsA     + 8388608;       //     65,536 f
  float* sens_tab = rec_tab  + 65536;         //    131,072 f

  k0_prep      <<<192, 256, 0, stream>>>(w, sigma, mu, erev, mask, sw, ssig, smu, serev, smask, rec_tab, sens_tab);
  k1_gemm_tanh <<<6144, 256, 0, stream>>>(inputs, W_in, b_in, hidden, gatet);
  k2_softmax_sig<<<8192, 256, 0, stream>>>(gatet);
  k3_cgemm     <<<2048, 256, 0, stream>>>(hidden, W_c, b_c, gatet, CG);
  k4_sensory   <<<256, 1024, 0, stream>>>(sens_tab, hidden, wnsA, wdsA);
  k5_recur     <<<256, 1024, 0, stream>>>(rec_tab, wnsA, wdsA, CG, cm, gleak, vleak, ode0, out2, out1);
  k6_ogemm     <<<1024, 256, 0, stream>>>(out2, W_out, b_out, out0);
}

// Round 2
// 3474.042 us; speedup vs baseline: 1.0030x; 1.0030x over previous
//
#include <hip/hip_runtime.h>
#include <math.h>

#define LOG2E 1.4426950408889634f

__device__ __forceinline__ float rcp_f(float x){ return __builtin_amdgcn_rcpf(x); }
__device__ __forceinline__ float exp2_f(float x){ return __builtin_amdgcn_exp2f(x); }
__device__ __forceinline__ float sigmoid_f(float x){ return rcp_f(1.0f + exp2_f(-x*LOG2E)); }
__device__ __forceinline__ float tanh_f(float x){
  x = fminf(fmaxf(x, -20.0f), 20.0f);
  float u = exp2_f(x * (2.0f*LOG2E));        // e^{2x}
  return (u - 1.0f) * rcp_f(u + 1.0f);
}

// ---------------- K0: pack nonlinearity tables ----------------
// rec_tab layout: [k][tid] float4 {sig_l2, musig_l2, w, w*erev}; tid: s=tid>>3, j=(tid&7)*16+k
// sens_tab layout: [half][k][tid] float4; tid: s=half*64+(tid>>4), i=(tid&15)*16+k
__global__ __launch_bounds__(256) void k0_prep(
    const float* __restrict__ w, const float* __restrict__ sigma, const float* __restrict__ mu,
    const float* __restrict__ erev, const float* __restrict__ smask_r,
    const float* __restrict__ sw, const float* __restrict__ ssigma, const float* __restrict__ smu,
    const float* __restrict__ serev, const float* __restrict__ smask_s,
    float* __restrict__ rec_tab, float* __restrict__ sens_tab){
  int p = blockIdx.x*256 + threadIdx.x;     // 49152 total
  if(p < 16384){
    int k = p >> 10, t5 = p & 1023;
    int s = t5 >> 3, j = (t5 & 7)*16 + k;
    int idx = j*128 + s;
    float sg = sigma[idx], m = mu[idx], wv = w[idx]*smask_r[idx], er = erev[idx];
    float4 o; o.x = sg*LOG2E; o.y = m*sg*LOG2E; o.z = wv; o.w = wv*er;
    *(float4*)(rec_tab + (size_t)p*4) = o;
  } else {
    int q = p - 16384;
    int half = q >> 14, r = q & 16383, k = r >> 10, t5 = r & 1023;
    int s = half*64 + (t5 >> 4), i = (t5 & 15)*16 + k;
    int idx = i*128 + s;
    float sg = ssigma[idx], m = smu[idx], wv = sw[idx]*smask_s[idx], er = serev[idx];
    float4 o; o.x = sg*LOG2E; o.y = m*sg*LOG2E; o.z = wv; o.w = wv*er;
    *(float4*)(sens_tab + (size_t)q*4) = o;
  }
}

// ---------------- K1: proj = tanh(X@W_in + b_in); hidden (b,t,0:256), gate (b,t,s) ----------------
// 128x128 tile, 256 threads, 8x8 per thread.
__global__ __launch_bounds__(256) void k1_gemm_tanh(
    const float* __restrict__ A, const float* __restrict__ Wb, const float* __restrict__ bias,
    float* __restrict__ hidden, float* __restrict__ gate){
  __shared__ float As[128][33];
  __shared__ float Bs[32][136];
  int wg = blockIdx.x;                    // 512*3
  int ntile = wg % 3, mtile = wg / 3;
  int row0 = mtile*128, col0 = ntile*128;
  int tid = threadIdx.x, ti = tid>>4, tj = tid&15;
  float acc[8][8] = {};
  for(int k0=0;k0<512;k0+=32){
    __syncthreads();
    #pragma unroll
    for(int l=0;l<4;l++){
      int idx = tid + l*256; int r = idx>>3, c4 = idx&7;
      float4 av = *(const float4*)(A + (size_t)(row0+r)*512 + k0 + c4*4);
      As[r][c4*4+0]=av.x; As[r][c4*4+1]=av.y; As[r][c4*4+2]=av.z; As[r][c4*4+3]=av.w;
    }
    #pragma unroll
    for(int l=0;l<4;l++){
      int idx = tid + l*256; int r = idx>>5, c4 = idx&31;
      *(float4*)&Bs[r][c4*4] = *(const float4*)(Wb + (size_t)(k0+r)*384 + col0 + c4*4);
    }
    __syncthreads();
    #pragma unroll
    for(int k=0;k<32;k++){
      float a[8];
      #pragma unroll
      for(int i=0;i<8;i++) a[i] = As[ti*8+i][k];
      float4 b0 = *(float4*)&Bs[k][tj*8];
      float4 b1 = *(float4*)&Bs[k][tj*8+4];
      #pragma unroll
      for(int i=0;i<8;i++){
        acc[i][0]=fmaf(a[i],b0.x,acc[i][0]); acc[i][1]=fmaf(a[i],b0.y,acc[i][1]);
        acc[i][2]=fmaf(a[i],b0.z,acc[i][2]); acc[i][3]=fmaf(a[i],b0.w,acc[i][3]);
        acc[i][4]=fmaf(a[i],b1.x,acc[i][4]); acc[i][5]=fmaf(a[i],b1.y,acc[i][5]);
        acc[i][6]=fmaf(a[i],b1.z,acc[i][6]); acc[i][7]=fmaf(a[i],b1.w,acc[i][7]);
      }
    }
  }
  float bv[8];
  #pragma unroll
  for(int j=0;j<8;j++) bv[j] = bias[col0 + tj*8 + j];
  if(col0 < 256){
    #pragma unroll
    for(int i=0;i<8;i++){
      float4 o0, o1;
      o0.x = tanh_f(acc[i][0]+bv[0]); o0.y = tanh_f(acc[i][1]+bv[1]);
      o0.z = tanh_f(acc[i][2]+bv[2]); o0.w = tanh_f(acc[i][3]+bv[3]);
      o1.x = tanh_f(acc[i][4]+bv[4]); o1.y = tanh_f(acc[i][5]+bv[5]);
      o1.z = tanh_f(acc[i][6]+bv[6]); o1.w = tanh_f(acc[i][7]+bv[7]);
      float* p = hidden + (size_t)(row0+ti*8+i)*256 + col0 + tj*8;
      *(float4*)p = o0; *(float4*)(p+4) = o1;
    }
  } else {
    #pragma unroll
    for(int i=0;i<8;i++){
      float4 o0, o1;
      o0.x = tanh_f(acc[i][0]+bv[0]); o0.y = tanh_f(acc[i][1]+bv[1]);
      o0.z = tanh_f(acc[i][2]+bv[2]); o0.w = tanh_f(acc[i][3]+bv[3]);
      o1.x = tanh_f(acc[i][4]+bv[4]); o1.y = tanh_f(acc[i][5]+bv[5]);
      o1.z = tanh_f(acc[i][6]+bv[6]); o1.w = tanh_f(acc[i][7]+bv[7]);
      float* p = gate + (size_t)(row0+ti*8+i)*128 + tj*8;
      *(float4*)p = o0; *(float4*)(p+4) = o1;
    }
  }
}

// ---------------- K2: softmax over T (axis=1) then sigmoid, in-place on gate (b,t,s) ----------------
// grid 256: b = wg>>2, sbase = (wg&3)*32. 1024 thr = 32 tl x 32 sq; 32 t-values in regs.
__global__ __launch_bounds__(1024) void k2_softmax_sig(float* __restrict__ gate){
  __shared__ float part[32][33];
  int wg = blockIdx.x;
  int b = wg >> 2, sbase = (wg & 3)*32;
  int tid = threadIdx.x, tl = tid >> 5, sq = tid & 31;
  float x[32];
  float mx = -1e30f;
  #pragma unroll
  for(int i=0;i<32;i++){
    int t = i*32 + tl;
    x[i] = gate[((size_t)b*1024 + t)*128 + sbase + sq];
    mx = fmaxf(mx, x[i]);
  }
  part[tl][sq] = mx;
  __syncthreads();
  float m = -1e30f;
  #pragma unroll
  for(int k=0;k<32;k++) m = fmaxf(m, part[k][sq]);
  float sm = 0.f;
  #pragma unroll
  for(int i=0;i<32;i++){ x[i] = exp2_f((x[i]-m)*LOG2E); sm += x[i]; }
  __syncthreads();
  part[tl][sq] = sm;
  __syncthreads();
  sm = 0.f;
  #pragma unroll
  for(int k=0;k<32;k++) sm += part[k][sq];
  float r = rcp_f(sm);
  #pragma unroll
  for(int i=0;i<32;i++){
    int t = i*32 + tl;
    gate[((size_t)b*1024 + t)*128 + sbase + sq] = sigmoid_f(x[i]*r);
  }
}

// ---------------- K3: CG = (hidden@W_c + b_c) * gsig ; 128x128 tile ----------------
__global__ __launch_bounds__(256) void k3_cgemm(
    const float* __restrict__ A, const float* __restrict__ Wb, const float* __restrict__ bias,
    const float* __restrict__ gsig, float* __restrict__ CG){
  __shared__ float As[128][33];
  __shared__ float Bs[32][136];
  int mtile = blockIdx.x;                  // 512
  int row0 = mtile*128;
  int tid = threadIdx.x, ti = tid>>4, tj = tid&15;
  float acc[8][8] = {};
  for(int k0=0;k0<256;k0+=32){
    __syncthreads();
    #pragma unroll
    for(int l=0;l<4;l++){
      int idx = tid + l*256; int r = idx>>3, c4 = idx&7;
      float4 av = *(const float4*)(A + (size_t)(row0+r)*256 + k0 + c4*4);
      As[r][c4*4+0]=av.x; As[r][c4*4+1]=av.y; As[r][c4*4+2]=av.z; As[r][c4*4+3]=av.w;
    }
    #pragma unroll
    for(int l=0;l<4;l++){
      int idx = tid + l*256; int r = idx>>5, c4 = idx&31;
      *(float4*)&Bs[r][c4*4] = *(const float4*)(Wb + (size_t)(k0+r)*128 + c4*4);
    }
    __syncthreads();
    #pragma unroll
    for(int k=0;k<32;k++){
      float a[8];
      #pragma unroll
      for(int i=0;i<8;i++) a[i] = As[ti*8+i][k];
      float4 b0 = *(float4*)&Bs[k][tj*8];
      float4 b1 = *(float4*)&Bs[k][tj*8+4];
      #pragma unroll
      for(int i=0;i<8;i++){
        acc[i][0]=fmaf(a[i],b0.x,acc[i][0]); acc[i][1]=fmaf(a[i],b0.y,acc[i][1]);
        acc[i][2]=fmaf(a[i],b0.z,acc[i][2]); acc[i][3]=fmaf(a[i],b0.w,acc[i][3]);
        acc[i][4]=fmaf(a[i],b1.x,acc[i][4]); acc[i][5]=fmaf(a[i],b1.y,acc[i][5]);
        acc[i][6]=fmaf(a[i],b1.z,acc[i][6]); acc[i][7]=fmaf(a[i],b1.w,acc[i][7]);
      }
    }
  }
  float bv[8];
  #pragma unroll
  for(int j=0;j<8;j++) bv[j] = bias[tj*8 + j];
  #pragma unroll
  for(int i=0;i<8;i++){
    size_t row = (size_t)(row0+ti*8+i);
    float4 g0 = *(const float4*)(gsig + row*128 + tj*8);
    float4 g1 = *(const float4*)(gsig + row*128 + tj*8+4);
    float4 o0, o1;
    o0.x = (acc[i][0]+bv[0])*g0.x; o0.y = (acc[i][1]+bv[1])*g0.y;
    o0.z = (acc[i][2]+bv[2])*g0.z; o0.w = (acc[i][3]+bv[3])*g0.w;
    o1.x = (acc[i][4]+bv[4])*g1.x; o1.y = (acc[i][5]+bv[5])*g1.y;
    o1.z = (acc[i][6]+bv[6])*g1.z; o1.w = (acc[i][7]+bv[7])*g1.w;
    float* p = CG + row*128 + tj*8;
    *(float4*)p = o0; *(float4*)(p+4) = o1;
  }
}

#define SIGACC(TT, VV) { float x_ = (TT).y - (VV)*(TT).x; float sg_ = rcp_f(1.0f + exp2_f(x_)); \
                         num = fmaf((TT).w, sg_, num); den = fmaf((TT).z, sg_, den); }

// ---------------- K4: sensory w_num_s / w_den_s for all (b,t,s) ----------------
__global__ __launch_bounds__(1024) void k4_sensory(
    const float* __restrict__ sens_tab, const float* __restrict__ hidden,
    float* __restrict__ wns, float* __restrict__ wds){
  int wg = blockIdx.x;                     // 1024
  int half = wg & 1;
  int btbase = wg >> 1;                    // 0..511
  int tid = threadIdx.x;
  float4 tab[16];
  #pragma unroll
  for(int k=0;k<16;k++) tab[k] = *(const float4*)(sens_tab + ((size_t)half*16384 + k*1024 + tid)*4);
  __shared__ float h_lds[320];
  __shared__ float res[128];
  int sloc = tid >> 4, ig = tid & 15;
  for(int bt = btbase; bt < 65536; bt += 512){
    __syncthreads();
    if(tid < 64){
      float4 hv = *(const float4*)(hidden + (size_t)bt*256 + tid*4);
      *(float4*)&h_lds[tid*4 + (tid>>2)*4] = hv;
    }
    __syncthreads();
    float num = 0.f, den = 0.f;
    #pragma unroll
    for(int k4=0;k4<4;k4++){
      float4 h4 = *(const float4*)&h_lds[ig*20 + k4*4];
      SIGACC(tab[k4*4+0], h4.x); SIGACC(tab[k4*4+1], h4.y);
      SIGACC(tab[k4*4+2], h4.z); SIGACC(tab[k4*4+3], h4.w);
    }
    num += __shfl_xor(num,1); den += __shfl_xor(den,1);
    num += __shfl_xor(num,2); den += __shfl_xor(den,2);
    num += __shfl_xor(num,4); den += __shfl_xor(den,4);
    num += __shfl_xor(num,8); den += __shfl_xor(den,8);
    if(ig==0){ res[sloc] = num; res[64+sloc] = den; }
    __syncthreads();
    if(tid < 64)       wns[(size_t)bt*128 + half*64 + tid] = res[tid];
    else if(tid < 128) wds[(size_t)bt*128 + half*64 + (tid-64)] = res[tid];
  }
}

// ---------------- K5: chunked-parallel recurrence ----------------
// 8 chunks x 64 batches = 512 WGs (2/CU); chunk len 128, warmup 10 steps
__global__ __launch_bounds__(1024) void k5_recur(
    const float* __restrict__ rec_tab, const float* __restrict__ wns, const float* __restrict__ wds,
    const float* __restrict__ CG, const float* __restrict__ cm, const float* __restrict__ gleak,
    const float* __restrict__ vleak, const float* __restrict__ ode0,
    float* __restrict__ out_fused, float* __restrict__ out_state){
  int wg = blockIdx.x;                     // 512
  int g = wg >> 6;                         // chunk 0..7
  int b = wg & 63;
  int tid = threadIdx.x;
  int s = tid >> 3, jg = tid & 7;
  float4 tab[16];
  #pragma unroll
  for(int k=0;k<16;k++) tab[k] = *(const float4*)(rec_tab + ((size_t)k*1024 + tid)*4);
  float cmt = cm[s]*6.0f;
  float gl  = gleak[s];
  float glv = gl*vleak[s];
  __shared__ float vbuf[2][160];
  __shared__ float wns_s[128];
  __shared__ float wds_s[128];
  if(tid < 128){
    float v0 = (g==0) ? ode0[b*128 + tid] : 0.0f;
    vbuf[0][tid + (tid>>4)*4] = v0;
  }
  int tstart = (g==0) ? 0 : g*128 - 10;
  int tend   = (g+1)*128;
  int tout   = g*128;
  int cur = 0;
  __syncthreads();
  for(int t=tstart; t<tend; t++){
    if(tid < 128)      wns_s[tid]     = wns[((size_t)b*1024 + t)*128 + tid];
    else if(tid < 256) wds_s[tid-128] = wds[((size_t)b*1024 + t)*128 + (tid-128)];
    __syncthreads();
    #pragma unroll
    for(int u=0; u<6; u++){
      float num = 0.f, den = 0.f;
      const float* vb = vbuf[cur];
      #pragma unroll
      for(int k4=0;k4<4;k4++){
        float4 v4 = *(const float4*)(vb + jg*20 + k4*4);
        SIGACC(tab[k4*4+0], v4.x); SIGACC(tab[k4*4+1], v4.y);
        SIGACC(tab[k4*4+2], v4.z); SIGACC(tab[k4*4+3], v4.w);
      }
      num += __shfl_xor(num,1); den += __shfl_xor(den,1);
      num += __shfl_xor(num,2); den += __shfl_xor(den,2);
      num += __shfl_xor(num,4); den += __shfl_xor(den,4);
      if(jg==0){
        float vold = vb[s + (s>>4)*4];
        float nn = fmaf(cmt, vold, glv) + num + wns_s[s];
        float dd = cmt + gl + den + wds_s[s] + 1e-8f;
        vbuf[cur^1][s + (s>>4)*4] = nn * rcp_f(dd);
      }
      cur ^= 1;
      __syncthreads();
    }
    if(t >= tout && tid < 128){
      float vv  = vbuf[cur][tid + (tid>>4)*4];
      float cgv = CG[((size_t)b*1024 + t)*128 + tid];
      out_fused[((size_t)b*1024 + t)*128 + tid] = vv * cgv;
    }
  }
  if(g==7 && tid<128) out_state[b*128 + tid] = vbuf[cur][tid + (tid>>4)*4];
}

// ---------------- K6: outputs = fused @ W_out + b_out ----------------
__global__ __launch_bounds__(256) void k6_ogemm(
    const float* __restrict__ A, const float* __restrict__ Wb, const float* __restrict__ bias,
    float* __restrict__ out0){
  __shared__ float As[64][36];
  __shared__ float Bs[32][64];
  int mtile = blockIdx.x;                  // 1024
  int row0 = mtile*64;
  int tid = threadIdx.x, tr = tid>>4, tc = tid&15;
  float acc[4][4] = {};
  for(int k0=0;k0<128;k0+=32){
    __syncthreads();
    #pragma unroll
    for(int l=0;l<2;l++){
      int idx = tid + l*256; int r = idx>>3, c4 = idx&7;
      *(float4*)&As[r][c4*4] = *(const float4*)(A + (size_t)(row0+r)*128 + k0 + c4*4);
    }
    #pragma unroll
    for(int l=0;l<2;l++){
      int idx = tid + l*256; int r = idx>>4, c4 = idx&15;
      *(float4*)&Bs[r][c4*4] = *(const float4*)(Wb + (size_t)(k0+r)*64 + c4*4);
    }
    __syncthreads();
    #pragma unroll
    for(int k=0;k<32;k++){
      float a0=As[tr*4+0][k],a1=As[tr*4+1][k],a2=As[tr*4+2][k],a3=As[tr*4+3][k];
      float4 b4 = *(float4*)&Bs[k][tc*4];
      acc[0][0]=fmaf(a0,b4.x,acc[0][0]); acc[0][1]=fmaf(a0,b4.y,acc[0][1]); acc[0][2]=fmaf(a0,b4.z,acc[0][2]); acc[0][3]=fmaf(a0,b4.w,acc[0][3]);
      acc[1][0]=fmaf(a1,b4.x,acc[1][0]); acc[1][1]=fmaf(a1,b4.y,acc[1][1]); acc[1][2]=fmaf(a1,b4.z,acc[1][2]); acc[1][3]=fmaf(a1,b4.w,acc[1][3]);
      acc[2][0]=fmaf(a2,b4.x,acc[2][0]); acc[2][1]=fmaf(a2,b4.y,acc[2][1]); acc[2][2]=fmaf(a2,b4.z,acc[2][2]); acc[2][3]=fmaf(a2,b4.w,acc[2][3]);
      acc[3][0]=fmaf(a3,b4.x,acc[3][0]); acc[3][1]=fmaf(a3,b4.y,acc[3][1]); acc[3][2]=fmaf(a3,b4.z,acc[3][2]); acc[3][3]=fmaf(a3,b4.w,acc[3][3]);
    }
  }
  float bv[4];
  #pragma unroll
  for(int j=0;j<4;j++) bv[j] = bias[tc*4 + j];
  #pragma unroll
  for(int i=0;i<4;i++){
    float4 o;
    o.x = acc[i][0]+bv[0]; o.y = acc[i][1]+bv[1];
    o.z = acc[i][2]+bv[2]; o.w = acc[i][3]+bv[3];
    *(float4*)(out0 + (size_t)(row0+tr*4+i)*64 + tc*4) = o;
  }
}

extern "C" void kernel_launch(void* const* d_in, const int* in_sizes, int n_in,
                              void* d_out, int out_size, void* d_ws, size_t ws_size,
                              hipStream_t stream) {
  const float* inputs = (const float*)d_in[0];
  const float* ode0   = (const float*)d_in[1];
  const float* W_in   = (const float*)d_in[2];
  const float* b_in   = (const float*)d_in[3];
  const float* W_c    = (const float*)d_in[4];
  const float* b_c    = (const float*)d_in[5];
  const float* W_out  = (const float*)d_in[6];
  const float* b_out  = (const float*)d_in[7];
  const float* gleak  = (const float*)d_in[8];
  const float* vleak  = (const float*)d_in[9];
  const float* cm     = (const float*)d_in[10];
  const float* w      = (const float*)d_in[11];
  const float* sigma  = (const float*)d_in[12];
  const float* mu     = (const float*)d_in[13];
  const float* sw     = (const float*)d_in[14];
  const float* ssig   = (const float*)d_in[15];
  const float* smu    = (const float*)d_in[16];
  const float* erev   = (const float*)d_in[17];
  const float* serev  = (const float*)d_in[18];
  const float* mask   = (const float*)d_in[19];
  const float* smask  = (const float*)d_in[20];

  float* out0 = (float*)d_out;                         // (B,T,M)
  float* out1 = out0 + (size_t)64*1024*64;             // (B,S)
  float* out2 = out1 + (size_t)64*128;                 // (B,T,S)

  float* ws       = (float*)d_ws;
  float* hidden   = ws;                       // 16,777,216 f  (b,t,i)
  float* gate     = hidden   + 16777216;      //  8,388,608 f  (b,t,s) -> gsig in-place
  float* CG       = gate     + 8388608;       //  8,388,608 f  (b,t,s)
  float* wnsA     = CG       + 8388608;       //  8,388,608 f
  float* wdsA     = wnsA     + 8388608;       //  8,388,608 f
  float* rec_tab  = wdsA     + 8388608;       //     65,536 f
  float* sens_tab = rec_tab  + 65536;         //    131,072 f

  k0_prep       <<<192, 256, 0, stream>>>(w, sigma, mu, erev, mask, sw, ssig, smu, serev, smask, rec_tab, sens_tab);
  k1_gemm_tanh  <<<1536, 256, 0, stream>>>(inputs, W_in, b_in, hidden, gate);
  k2_softmax_sig<<<256, 1024, 0, stream>>>(gate);
  k3_cgemm      <<<512, 256, 0, stream>>>(hidden, W_c, b_c, gate, CG);
  k4_sensory    <<<1024, 1024, 0, stream>>>(sens_tab, hidden, wnsA, wdsA);
  k5_recur      <<<512, 1024, 0, stream>>>(rec_tab, wnsA, wdsA, CG, cm, gleak, vleak, ode0, out2, out1);
  k6_ogemm      <<<1024, 256, 0, stream>>>(out2, W_out, b_out, out0);
}

// Round 4
// 3178.396 us; speedup vs baseline: 1.0962x; 1.0930x over previous
//
#include <hip/hip_runtime.h>
#include <math.h>

#define LOG2E 1.4426950408889634f

__device__ __forceinline__ float rcp_f(float x){ return __builtin_amdgcn_rcpf(x); }
__device__ __forceinline__ float exp2_f(float x){ return __builtin_amdgcn_exp2f(x); }
__device__ __forceinline__ float sigmoid_f(float x){ return rcp_f(1.0f + exp2_f(-x*LOG2E)); }
__device__ __forceinline__ float tanh_f(float x){
  x = fminf(fmaxf(x, -20.0f), 20.0f);
  float u = exp2_f(x * (2.0f*LOG2E));        // e^{2x}
  return (u - 1.0f) * rcp_f(u + 1.0f);
}

// ---------------- K0: pack nonlinearity tables ----------------
// rec_tab layout: [k][tid] float4 {sig_l2, musig_l2, w, w*erev}; tid: s=tid>>3, j=(tid&7)*16+k
// sens_tab layout: [half][k][tid] float4; tid: s=half*64+(tid>>4), i=(tid&15)*16+k
__global__ __launch_bounds__(256) void k0_prep(
    const float* __restrict__ w, const float* __restrict__ sigma, const float* __restrict__ mu,
    const float* __restrict__ erev, const float* __restrict__ smask_r,
    const float* __restrict__ sw, const float* __restrict__ ssigma, const float* __restrict__ smu,
    const float* __restrict__ serev, const float* __restrict__ smask_s,
    float* __restrict__ rec_tab, float* __restrict__ sens_tab){
  int p = blockIdx.x*256 + threadIdx.x;     // 49152 total
  if(p < 16384){
    int k = p >> 10, t5 = p & 1023;
    int s = t5 >> 3, j = (t5 & 7)*16 + k;
    int idx = j*128 + s;
    float sg = sigma[idx], m = mu[idx], wv = w[idx]*smask_r[idx], er = erev[idx];
    float4 o; o.x = sg*LOG2E; o.y = m*sg*LOG2E; o.z = wv; o.w = wv*er;
    *(float4*)(rec_tab + (size_t)p*4) = o;
  } else {
    int q = p - 16384;
    int half = q >> 14, r = q & 16383, k = r >> 10, t5 = r & 1023;
    int s = half*64 + (t5 >> 4), i = (t5 & 15)*16 + k;
    int idx = i*128 + s;
    float sg = ssigma[idx], m = smu[idx], wv = sw[idx]*smask_s[idx], er = serev[idx];
    float4 o; o.x = sg*LOG2E; o.y = m*sg*LOG2E; o.z = wv; o.w = wv*er;
    *(float4*)(sens_tab + (size_t)q*4) = o;
  }
}

// ---------------- K1: proj = tanh(X@W_in + b_in); hidden (b,t,0:256), gate (b,t,s) ----------------
// 128x128 tile, 256 threads, 8x8 per thread.
__global__ __launch_bounds__(256) void k1_gemm_tanh(
    const float* __restrict__ A, const float* __restrict__ Wb, const float* __restrict__ bias,
    float* __restrict__ hidden, float* __restrict__ gate){
  __shared__ float As[128][33];
  __shared__ float Bs[32][136];
  int wg = blockIdx.x;                    // 512*3
  int ntile = wg % 3, mtile = wg / 3;
  int row0 = mtile*128, col0 = ntile*128;
  int tid = threadIdx.x, ti = tid>>4, tj = tid&15;
  float acc[8][8] = {};
  for(int k0=0;k0<512;k0+=32){
    __syncthreads();
    #pragma unroll
    for(int l=0;l<4;l++){
      int idx = tid + l*256; int r = idx>>3, c4 = idx&7;
      float4 av = *(const float4*)(A + (size_t)(row0+r)*512 + k0 + c4*4);
      As[r][c4*4+0]=av.x; As[r][c4*4+1]=av.y; As[r][c4*4+2]=av.z; As[r][c4*4+3]=av.w;
    }
    #pragma unroll
    for(int l=0;l<4;l++){
      int idx = tid + l*256; int r = idx>>5, c4 = idx&31;
      *(float4*)&Bs[r][c4*4] = *(const float4*)(Wb + (size_t)(k0+r)*384 + col0 + c4*4);
    }
    __syncthreads();
    #pragma unroll
    for(int k=0;k<32;k++){
      float a[8];
      #pragma unroll
      for(int i=0;i<8;i++) a[i] = As[ti*8+i][k];
      float4 b0 = *(float4*)&Bs[k][tj*8];
      float4 b1 = *(float4*)&Bs[k][tj*8+4];
      #pragma unroll
      for(int i=0;i<8;i++){
        acc[i][0]=fmaf(a[i],b0.x,acc[i][0]); acc[i][1]=fmaf(a[i],b0.y,acc[i][1]);
        acc[i][2]=fmaf(a[i],b0.z,acc[i][2]); acc[i][3]=fmaf(a[i],b0.w,acc[i][3]);
        acc[i][4]=fmaf(a[i],b1.x,acc[i][4]); acc[i][5]=fmaf(a[i],b1.y,acc[i][5]);
        acc[i][6]=fmaf(a[i],b1.z,acc[i][6]); acc[i][7]=fmaf(a[i],b1.w,acc[i][7]);
      }
    }
  }
  float bv[8];
  #pragma unroll
  for(int j=0;j<8;j++) bv[j] = bias[col0 + tj*8 + j];
  if(col0 < 256){
    #pragma unroll
    for(int i=0;i<8;i++){
      float4 o0, o1;
      o0.x = tanh_f(acc[i][0]+bv[0]); o0.y = tanh_f(acc[i][1]+bv[1]);
      o0.z = tanh_f(acc[i][2]+bv[2]); o0.w = tanh_f(acc[i][3]+bv[3]);
      o1.x = tanh_f(acc[i][4]+bv[4]); o1.y = tanh_f(acc[i][5]+bv[5]);
      o1.z = tanh_f(acc[i][6]+bv[6]); o1.w = tanh_f(acc[i][7]+bv[7]);
      float* p = hidden + (size_t)(row0+ti*8+i)*256 + col0 + tj*8;
      *(float4*)p = o0; *(float4*)(p+4) = o1;
    }
  } else {
    #pragma unroll
    for(int i=0;i<8;i++){
      float4 o0, o1;
      o0.x = tanh_f(acc[i][0]+bv[0]); o0.y = tanh_f(acc[i][1]+bv[1]);
      o0.z = tanh_f(acc[i][2]+bv[2]); o0.w = tanh_f(acc[i][3]+bv[3]);
      o1.x = tanh_f(acc[i][4]+bv[4]); o1.y = tanh_f(acc[i][5]+bv[5]);
      o1.z = tanh_f(acc[i][6]+bv[6]); o1.w = tanh_f(acc[i][7]+bv[7]);
      float* p = gate + (size_t)(row0+ti*8+i)*128 + tj*8;
      *(float4*)p = o0; *(float4*)(p+4) = o1;
    }
  }
}

// ---------------- K2: softmax over T (axis=1) then sigmoid, in-place on gate (b,t,s) ----------------
__global__ __launch_bounds__(1024) void k2_softmax_sig(float* __restrict__ gate){
  __shared__ float part[32][33];
  int wg = blockIdx.x;
  int b = wg >> 2, sbase = (wg & 3)*32;
  int tid = threadIdx.x, tl = tid >> 5, sq = tid & 31;
  float x[32];
  float mx = -1e30f;
  #pragma unroll
  for(int i=0;i<32;i++){
    int t = i*32 + tl;
    x[i] = gate[((size_t)b*1024 + t)*128 + sbase + sq];
    mx = fmaxf(mx, x[i]);
  }
  part[tl][sq] = mx;
  __syncthreads();
  float m = -1e30f;
  #pragma unroll
  for(int k=0;k<32;k++) m = fmaxf(m, part[k][sq]);
  float sm = 0.f;
  #pragma unroll
  for(int i=0;i<32;i++){ x[i] = exp2_f((x[i]-m)*LOG2E); sm += x[i]; }
  __syncthreads();
  part[tl][sq] = sm;
  __syncthreads();
  sm = 0.f;
  #pragma unroll
  for(int k=0;k<32;k++) sm += part[k][sq];
  float r = rcp_f(sm);
  #pragma unroll
  for(int i=0;i<32;i++){
    int t = i*32 + tl;
    gate[((size_t)b*1024 + t)*128 + sbase + sq] = sigmoid_f(x[i]*r);
  }
}

// ---------------- K3: CG = (hidden@W_c + b_c) * gsig ; 128x128 tile ----------------
__global__ __launch_bounds__(256) void k3_cgemm(
    const float* __restrict__ A, const float* __restrict__ Wb, const float* __restrict__ bias,
    const float* __restrict__ gsig, float* __restrict__ CG){
  __shared__ float As[128][33];
  __shared__ float Bs[32][136];
  int mtile = blockIdx.x;                  // 512
  int row0 = mtile*128;
  int tid = threadIdx.x, ti = tid>>4, tj = tid&15;
  float acc[8][8] = {};
  for(int k0=0;k0<256;k0+=32){
    __syncthreads();
    #pragma unroll
    for(int l=0;l<4;l++){
      int idx = tid + l*256; int r = idx>>3, c4 = idx&7;
      float4 av = *(const float4*)(A + (size_t)(row0+r)*256 + k0 + c4*4);
      As[r][c4*4+0]=av.x; As[r][c4*4+1]=av.y; As[r][c4*4+2]=av.z; As[r][c4*4+3]=av.w;
    }
    #pragma unroll
    for(int l=0;l<4;l++){
      int idx = tid + l*256; int r = idx>>5, c4 = idx&31;
      *(float4*)&Bs[r][c4*4] = *(const float4*)(Wb + (size_t)(k0+r)*128 + c4*4);
    }
    __syncthreads();
    #pragma unroll
    for(int k=0;k<32;k++){
      float a[8];
      #pragma unroll
      for(int i=0;i<8;i++) a[i] = As[ti*8+i][k];
      float4 b0 = *(float4*)&Bs[k][tj*8];
      float4 b1 = *(float4*)&Bs[k][tj*8+4];
      #pragma unroll
      for(int i=0;i<8;i++){
        acc[i][0]=fmaf(a[i],b0.x,acc[i][0]); acc[i][1]=fmaf(a[i],b0.y,acc[i][1]);
        acc[i][2]=fmaf(a[i],b0.z,acc[i][2]); acc[i][3]=fmaf(a[i],b0.w,acc[i][3]);
        acc[i][4]=fmaf(a[i],b1.x,acc[i][4]); acc[i][5]=fmaf(a[i],b1.y,acc[i][5]);
        acc[i][6]=fmaf(a[i],b1.z,acc[i][6]); acc[i][7]=fmaf(a[i],b1.w,acc[i][7]);
      }
    }
  }
  float bv[8];
  #pragma unroll
  for(int j=0;j<8;j++) bv[j] = bias[tj*8 + j];
  #pragma unroll
  for(int i=0;i<8;i++){
    size_t row = (size_t)(row0+ti*8+i);
    float4 g0 = *(const float4*)(gsig + row*128 + tj*8);
    float4 g1 = *(const float4*)(gsig + row*128 + tj*8+4);
    float4 o0, o1;
    o0.x = (acc[i][0]+bv[0])*g0.x; o0.y = (acc[i][1]+bv[1])*g0.y;
    o0.z = (acc[i][2]+bv[2])*g0.z; o0.w = (acc[i][3]+bv[3])*g0.w;
    o1.x = (acc[i][4]+bv[4])*g1.x; o1.y = (acc[i][5]+bv[5])*g1.y;
    o1.z = (acc[i][6]+bv[6])*g1.z; o1.w = (acc[i][7]+bv[7])*g1.w;
    float* p = CG + row*128 + tj*8;
    *(float4*)p = o0; *(float4*)(p+4) = o1;
  }
}

#define SIGACC(TT, VV) { float x_ = (TT).y - (VV)*(TT).x; float sg_ = rcp_f(1.0f + exp2_f(x_)); \
                         num = fmaf((TT).w, sg_, num); den = fmaf((TT).z, sg_, den); }

// ---------------- K4: sensory w_num_s / w_den_s, software-pipelined ----------------
// grid 256: half = wg&1, btbase = wg>>1 (0..127); 512 iterations, prefetch distance 2.
__global__ __launch_bounds__(1024) void k4_sensory(
    const float* __restrict__ sens_tab, const float* __restrict__ hidden,
    float* __restrict__ wns, float* __restrict__ wds){
  int wg = blockIdx.x;                     // 256
  int half = wg & 1;
  int btbase = wg >> 1;                    // 0..127
  int tid = threadIdx.x;
  float4 tab[16];
  #pragma unroll
  for(int k=0;k<16;k++) tab[k] = *(const float4*)(sens_tab + ((size_t)half*16384 + k*1024 + tid)*4);
  __shared__ float h_lds[2][320];
  int sloc = tid >> 4, ig = tid & 15;
  float4 h4 = make_float4(0.f,0.f,0.f,0.f);
  if(tid < 64){
    float4 t0 = *(const float4*)(hidden + (size_t)btbase*256 + tid*4);
    *(float4*)&h_lds[0][tid*4 + (tid>>2)*4] = t0;
    h4 = *(const float4*)(hidden + (size_t)(btbase+128)*256 + tid*4);
  }
  int cur = 0;
  for(int i=0;i<512;i++){
    int bt = btbase + i*128;
    __syncthreads();
    if(tid < 64){
      if(i+1 < 512) *(float4*)&h_lds[cur^1][tid*4 + (tid>>2)*4] = h4;
      if(i+2 < 512) h4 = *(const float4*)(hidden + (size_t)(bt+256)*256 + tid*4);
    }
    float num = 0.f, den = 0.f;
    #pragma unroll
    for(int k4=0;k4<4;k4++){
      float4 hh = *(const float4*)&h_lds[cur][ig*20 + k4*4];
      SIGACC(tab[k4*4+0], hh.x); SIGACC(tab[k4*4+1], hh.y);
      SIGACC(tab[k4*4+2], hh.z); SIGACC(tab[k4*4+3], hh.w);
    }
    num += __shfl_xor(num,1); den += __shfl_xor(den,1);
    num += __shfl_xor(num,2); den += __shfl_xor(den,2);
    num += __shfl_xor(num,4); den += __shfl_xor(den,4);
    num += __shfl_xor(num,8); den += __shfl_xor(den,8);
    if(ig == 0){
      wns[(size_t)bt*128 + half*64 + sloc] = num;
      wds[(size_t)bt*128 + half*64 + sloc] = den;
    }
    cur ^= 1;
  }
}

// ---------------- K5: chunked-parallel recurrence, 2 batches per WG ----------------
// 8 chunks x 32 b-pairs = 256 WGs (1/CU, one round); chunk len 128, warmup 10.
// The (j,s) table is batch-independent -> both batches share the VGPR table and
// each __syncthreads covers 2x the SIGACC work (barrier idle ~halved).
__global__ __launch_bounds__(1024) void k5_recur(
    const float* __restrict__ rec_tab, const float* __restrict__ wns, const float* __restrict__ wds,
    const float* __restrict__ CG, const float* __restrict__ cm, const float* __restrict__ gleak,
    const float* __restrict__ vleak, const float* __restrict__ ode0,
    float* __restrict__ out_fused, float* __restrict__ out_state){
  int wg = blockIdx.x;                     // 256
  int g = wg >> 5;                         // chunk 0..7
  int bp = wg & 31;
  int b0 = bp*2;
  int tid = threadIdx.x;
  int s = tid >> 3, jg = tid & 7;
  float4 tab[16];
  #pragma unroll
  for(int k=0;k<16;k++) tab[k] = *(const float4*)(rec_tab + ((size_t)k*1024 + tid)*4);
  float cmt = cm[s]*6.0f;
  float gl  = gleak[s];
  float glv = gl*vleak[s];
  __shared__ float vbuf[2][2][160];        // [b2][cur][padded s]
  __shared__ float wns_s[2][128];
  __shared__ float wds_s[2][128];
  if(tid < 256){
    int b2 = tid >> 7, ss = tid & 127;
    float v0 = (g==0) ? ode0[(b0+b2)*128 + ss] : 0.0f;
    vbuf[b2][0][ss + (ss>>4)*4] = v0;
  }
  int tstart = (g==0) ? 0 : g*128 - 10;
  int tend   = (g+1)*128;
  int tout   = g*128;
  int cur = 0;
  __syncthreads();
  for(int t=tstart; t<tend; t++){
    if(tid < 512){
      int q = tid >> 7, idx = tid & 127;
      int b2 = q >> 1;
      size_t base = ((size_t)(b0+b2)*1024 + t)*128 + idx;
      if(q & 1) wds_s[b2][idx] = wds[base];
      else      wns_s[b2][idx] = wns[base];
    }
    __syncthreads();
    #pragma unroll
    for(int u=0; u<6; u++){
      #pragma unroll
      for(int b2=0; b2<2; b2++){
        float num = 0.f, den = 0.f;
        const float* vb = vbuf[b2][cur];
        #pragma unroll
        for(int k4=0;k4<4;k4++){
          float4 v4 = *(const float4*)(vb + jg*20 + k4*4);
          SIGACC(tab[k4*4+0], v4.x); SIGACC(tab[k4*4+1], v4.y);
          SIGACC(tab[k4*4+2], v4.z); SIGACC(tab[k4*4+3], v4.w);
        }
        num += __shfl_xor(num,1); den += __shfl_xor(den,1);
        num += __shfl_xor(num,2); den += __shfl_xor(den,2);
        num += __shfl_xor(num,4); den += __shfl_xor(den,4);
        if(jg == 0){
          float vold = vb[s + (s>>4)*4];
          float nn = fmaf(cmt, vold, glv) + num + wns_s[b2][s];
          float dd = cmt + gl + den + wds_s[b2][s] + 1e-8f;
          vbuf[b2][cur^1][s + (s>>4)*4] = nn * rcp_f(dd);
        }
      }
      cur ^= 1;
      __syncthreads();
    }
    if(t >= tout && tid < 256){
      int b2 = tid >> 7, ss = tid & 127;
      float vv  = vbuf[b2][cur][ss + (ss>>4)*4];
      float cgv = CG[((size_t)(b0+b2)*1024 + t)*128 + ss];
      out_fused[((size_t)(b0+b2)*1024 + t)*128 + ss] = vv * cgv;
    }
  }
  if(g==7 && tid < 256){
    int b2 = tid >> 7, ss = tid & 127;
    out_state[(b0+b2)*128 + ss] = vbuf[b2][cur][ss + (ss>>4)*4];
  }
}

// ---------------- K6: outputs = fused @ W_out + b_out ----------------
__global__ __launch_bounds__(256) void k6_ogemm(
    const float* __restrict__ A, const float* __restrict__ Wb, const float* __restrict__ bias,
    float* __restrict__ out0){
  __shared__ float As[64][36];
  __shared__ float Bs[32][64];
  int mtile = blockIdx.x;                  // 1024
  int row0 = mtile*64;
  int tid = threadIdx.x, tr = tid>>4, tc = tid&15;
  float acc[4][4] = {};
  for(int k0=0;k0<128;k0+=32){
    __syncthreads();
    #pragma unroll
    for(int l=0;l<2;l++){
      int idx = tid + l*256; int r = idx>>3, c4 = idx&7;
      *(float4*)&As[r][c4*4] = *(const float4*)(A + (size_t)(row0+r)*128 + k0 + c4*4);
    }
    #pragma unroll
    for(int l=0;l<2;l++){
      int idx = tid + l*256; int r = idx>>4, c4 = idx&15;
      *(float4*)&Bs[r][c4*4] = *(const float4*)(Wb + (size_t)(k0+r)*64 + c4*4);
    }
    __syncthreads();
    #pragma unroll
    for(int k=0;k<32;k++){
      float a0=As[tr*4+0][k],a1=As[tr*4+1][k],a2=As[tr*4+2][k],a3=As[tr*4+3][k];
      float4 b4 = *(float4*)&Bs[k][tc*4];
      acc[0][0]=fmaf(a0,b4.x,acc[0][0]); acc[0][1]=fmaf(a0,b4.y,acc[0][1]); acc[0][2]=fmaf(a0,b4.z,acc[0][2]); acc[0][3]=fmaf(a0,b4.w,acc[0][3]);
      acc[1][0]=fmaf(a1,b4.x,acc[1][0]); acc[1][1]=fmaf(a1,b4.y,acc[1][1]); acc[1][2]=fmaf(a1,b4.z,acc[1][2]); acc[1][3]=fmaf(a1,b4.w,acc[1][3]);
      acc[2][0]=fmaf(a2,b4.x,acc[2][0]); acc[2][1]=fmaf(a2,b4.y,acc[2][1]); acc[2][2]=fmaf(a2,b4.z,acc[2][2]); acc[2][3]=fmaf(a2,b4.w,acc[2][3]);
      acc[3][0]=fmaf(a3,b4.x,acc[3][0]); acc[3][1]=fmaf(a3,b4.y,acc[3][1]); acc[3][2]=fmaf(a3,b4.z,acc[3][2]); acc[3][3]=fmaf(a3,b4.w,acc[3][3]);
    }
  }
  float bv[4];
  #pragma unroll
  for(int j=0;j<4;j++) bv[j] = bias[tc*4 + j];
  #pragma unroll
  for(int i=0;i<4;i++){
    float4 o;
    o.x = acc[i][0]+bv[0]; o.y = acc[i][1]+bv[1];
    o.z = acc[i][2]+bv[2]; o.w = acc[i][3]+bv[3];
    *(float4*)(out0 + (size_t)(row0+tr*4+i)*64 + tc*4) = o;
  }
}

extern "C" void kernel_launch(void* const* d_in, const int* in_sizes, int n_in,
                              void* d_out, int out_size, void* d_ws, size_t ws_size,
                              hipStream_t stream) {
  const float* inputs = (const float*)d_in[0];
  const float* ode0   = (const float*)d_in[1];
  const float* W_in   = (const float*)d_in[2];
  const float* b_in   = (const float*)d_in[3];
  const float* W_c    = (const float*)d_in[4];
  const float* b_c    = (const float*)d_in[5];
  const float* W_out  = (const float*)d_in[6];
  const float* b_out  = (const float*)d_in[7];
  const float* gleak  = (const float*)d_in[8];
  const float* vleak  = (const float*)d_in[9];
  const float* cm     = (const float*)d_in[10];
  const float* w      = (const float*)d_in[11];
  const float* sigma  = (const float*)d_in[12];
  const float* mu     = (const float*)d_in[13];
  const float* sw     = (const float*)d_in[14];
  const float* ssig   = (const float*)d_in[15];
  const float* smu    = (const float*)d_in[16];
  const float* erev   = (const float*)d_in[17];
  const float* serev  = (const float*)d_in[18];
  const float* mask   = (const float*)d_in[19];
  const float* smask  = (const float*)d_in[20];

  float* out0 = (float*)d_out;                         // (B,T,M)
  float* out1 = out0 + (size_t)64*1024*64;             // (B,S)
  float* out2 = out1 + (size_t)64*128;                 // (B,T,S)

  float* ws       = (float*)d_ws;
  float* hidden   = ws;                       // 16,777,216 f  (b,t,i)
  float* gate     = hidden   + 16777216;      //  8,388,608 f  (b,t,s) -> gsig in-place
  float* CG       = gate     + 8388608;       //  8,388,608 f  (b,t,s)
  float* wnsA     = CG       + 8388608;       //  8,388,608 f
  float* wdsA     = wnsA     + 8388608;       //  8,388,608 f
  float* rec_tab  = wdsA     + 8388608;       //     65,536 f
  float* sens_tab = rec_tab  + 65536;         //    131,072 f

  k0_prep       <<<192, 256, 0, stream>>>(w, sigma, mu, erev, mask, sw, ssig, smu, serev, smask, rec_tab, sens_tab);
  k1_gemm_tanh  <<<1536, 256, 0, stream>>>(inputs, W_in, b_in, hidden, gate);
  k2_softmax_sig<<<256, 1024, 0, stream>>>(gate);
  k3_cgemm      <<<512, 256, 0, stream>>>(hidden, W_c, b_c, gate, CG);
  k4_sensory    <<<256, 1024, 0, stream>>>(sens_tab, hidden, wnsA, wdsA);
  k5_recur      <<<256, 1024, 0, stream>>>(rec_tab, wnsA, wdsA, CG, cm, gleak, vleak, ode0, out2, out1);
  k6_ogemm      <<<1024, 256, 0, stream>>>(out2, W_out, b_out, out0);
}